// Round 22
// baseline (435.187 us; speedup 1.0000x reference)
//
#include <hip/hip_runtime.h>

#define C 16
#define NIMG 24
#define H 96
#define W 192
#define PX (H*W)            // 18432
#define LOG2E 1.44269504088896f

typedef float v2f  __attribute__((ext_vector_type(2)));
typedef float v4f  __attribute__((ext_vector_type(4)));
typedef short v8s  __attribute__((ext_vector_type(8)));

// workspace float offsets
#define QP_OFF 0                                // float2 [n][px]
#define KP_OFF (NIMG*PX*2)                      // float2 [n][px]
#define VB4_OFF (2*NIMG*PX*2)                   // ushort4 [n][h][c4][w]
#define VBP_OFF (VB4_OFF + NIMG*PX*8)           // ushort [n][h][c][w]
#define KB_OFF  (VBP_OFF + NIMG*PX*8)           // ushort [n][2][h][w]
#define GM_OFF  (KB_OFF + NIMG*PX)              // float gmp [n][8][2]
#define SC_OFF  (GM_OFF + 384)                  // float s_col [n][h][w]
#define ACC_OFF (SC_OFF + NIMG*PX)              // ushort accC [n][h][w][c]
// end ~13.27M floats (~53 MB)

__device__ __forceinline__ unsigned short f2bf(float x) {
    union { float f; unsigned u; } v; v.f = x;
    unsigned r = v.u + 0x7fffu + ((v.u >> 16) & 1u);   // RNE
    return (unsigned short)(r >> 16);
}
__device__ __forceinline__ float bf2f(unsigned short u) {
    union { unsigned u; float f; } v; v.u = ((unsigned)u) << 16;
    return v.f;
}

__global__ __launch_bounds__(256)
void qkv_kernel(const float* __restrict__ x, long xn_s, long xc_s,
                const float* __restrict__ qw, const float* __restrict__ qb,
                const float* __restrict__ kw, const float* __restrict__ kb,
                const float* __restrict__ vw, const float* __restrict__ vb,
                float2* __restrict__ Qp, float2* __restrict__ Kp,
                ushort4* __restrict__ Vb4, unsigned short* __restrict__ Vbp,
                unsigned short* __restrict__ Kb)
{
    __shared__ float wq[2*C+2], wk[2*C+2], wv[C*C+C];
    int tid = threadIdx.x;
    if (tid < 2*C) { wq[tid] = qw[tid]; wk[tid] = kw[tid]; }
    if (tid < 2)   { wq[2*C+tid] = qb[tid]; wk[2*C+tid] = kb[tid]; }
    if (tid < C*C) wv[tid] = vw[tid];
    if (tid < C)   wv[C*C+tid] = vb[tid];
    __syncthreads();

    int id = blockIdx.x*256 + tid;        // 0 .. 442367
    int n  = id / PX;
    int p  = id - n*PX;
    int h  = p / W;
    int w  = p - h*W;
    const float* xp = x + (long)n*xn_s + p;

    float xv[C];
    #pragma unroll
    for (int c = 0; c < C; c++) xv[c] = xp[(long)c*xc_s];

    float q0 = wq[2*C], q1 = wq[2*C+1];
    float k0 = wk[2*C], k1 = wk[2*C+1];
    #pragma unroll
    for (int c = 0; c < C; c++) {
        q0 += wq[c]*xv[c];   q1 += wq[C+c]*xv[c];
        k0 += wk[c]*xv[c];   k1 += wk[C+c]*xv[c];
    }
    Qp[id] = make_float2(q0, q1);
    Kp[id] = make_float2(k0, k1);
    Kb[((long)(n*2+0)*H + h)*W + w] = f2bf(k0);
    Kb[((long)(n*2+1)*H + h)*W + w] = f2bf(k1);

    float vv[C];
    #pragma unroll
    for (int o = 0; o < C; o++) {
        float a = wv[C*C+o];
        #pragma unroll
        for (int c = 0; c < C; c++) a += wv[o*C+c]*xv[c];
        vv[o] = a;
    }
    unsigned short vb16[C];
    #pragma unroll
    for (int o = 0; o < C; o++) vb16[o] = f2bf(vv[o]);

    #pragma unroll
    for (int c4 = 0; c4 < 4; c4++) {
        ushort4 u;
        u.x = vb16[c4*4+0]; u.y = vb16[c4*4+1];
        u.z = vb16[c4*4+2]; u.w = vb16[c4*4+3];
        Vb4[(((long)n*H + h)*4 + c4)*W + w] = u;
    }
    #pragma unroll
    for (int o = 0; o < C; o++)
        Vbp[(((long)n*H + h)*16 + o)*W + w] = vb16[o];
}

// Per-image |K| maxima, two-stage: 192 blocks (8 slices/image), plain stores.
__global__ __launch_bounds__(256)
void gmax_kernel(const float2* __restrict__ Kp, float* __restrict__ gmp)
{
    __shared__ float red0[4], red1[4];
    int bid = blockIdx.x;          // 0..191
    int n   = bid >> 3;
    int sl  = bid & 7;
    int tid = threadIdx.x;
    const float2* base = Kp + (long)n*PX + sl*(PX/8);

    float a0 = 0.f, a1 = 0.f;
    #pragma unroll 3
    for (int i = tid; i < PX/8; i += 256) {
        float2 k = base[i];
        a0 = fmaxf(a0, fabsf(k.x));
        a1 = fmaxf(a1, fabsf(k.y));
    }
    #pragma unroll
    for (int d = 1; d < 64; d <<= 1) {
        a0 = fmaxf(a0, __shfl_xor(a0, d));
        a1 = fmaxf(a1, __shfl_xor(a1, d));
    }
    if ((tid & 63) == 0) { red0[tid >> 6] = a0; red1[tid >> 6] = a1; }
    __syncthreads();
    if (tid == 0) {
        gmp[(n*8 + sl)*2 + 0] = fmaxf(fmaxf(red0[0], red0[1]), fmaxf(red0[2], red0[3]));
        gmp[(n*8 + sl)*2 + 1] = fmaxf(fmaxf(red1[0], red1[1]), fmaxf(red1[2], red1[3]));
    }
}

__device__ __forceinline__ void gm_reduce(const float* __restrict__ gmp, int n,
                                          float& g0, float& g1)
{
    g0 = 0.f; g1 = 0.f;
    #pragma unroll
    for (int s = 0; s < 8; s++) {
        g0 = fmaxf(g0, gmp[(n*8 + s)*2 + 0]);
        g1 = fmaxf(g1, gmp[(n*8 + s)*2 + 1]);
    }
}

// Column (H) attention as MFMA (R18 structure, scalar shift bound).
#define VT_WS 1672   // per-w Vt stride in ushorts: 16*104 + 8 pad
__global__ __launch_bounds__(256)
void col_attn_kernel(const float2* __restrict__ Qp, const float2* __restrict__ Kp,
                     const ushort4* __restrict__ Vb4,
                     const float* __restrict__ gmp,
                     unsigned short* __restrict__ accC, float* __restrict__ sC)
{
    __shared__ unsigned short Vt[4*VT_WS];      // V^T: [wl][c][j] bf16, j-pad 104
    __shared__ unsigned short Ks[4*2*96];       // K:   [wl][ch][j] bf16

    const int chunk = (NIMG*48) / 8;            // 144 ; 1152 % 8 == 0
    int bid = blockIdx.x;
    int swz = (bid & 7)*chunk + (bid >> 3);
    int n   = swz / 48;
    int wg  = swz - n*48;
    int w0  = wg*4;
    int tid = threadIdx.x;

    const float2* Qpn = Qp + n*PX;
    const float2* Kpn = Kp + n*PX;
    const ushort4* Vbn = Vb4 + (long)n*PX*4;
    float g0, g1;
    gm_reduce(gmp, n, g0, g1);

    // ---- stage V^T (1536 ushort4, 6/thread) ----
    #pragma unroll
    for (int i = 0; i < 6; i++) {
        int idx = i*256 + tid;        // 0..1535
        int wl  = idx & 3;
        int c4  = (idx >> 2) & 3;
        int j   = idx >> 4;           // 0..95
        ushort4 v = Vbn[((long)j*4 + c4)*W + w0 + wl];
        int b = wl*VT_WS + (c4*4)*104 + j;
        Vt[b        ] = v.x;
        Vt[b + 104  ] = v.y;
        Vt[b + 208  ] = v.z;
        Vt[b + 312  ] = v.w;
    }
    // ---- stage K (384 float2 -> bf16) ----
    #pragma unroll
    for (int i = 0; i < 2; i++) {
        int idx = i*256 + tid;
        if (idx < 384) {
            int wl = idx & 3;
            int j  = idx >> 2;
            float2 kk = Kpn[j*W + w0 + wl];
            Ks[wl*192 + j]      = f2bf(kk.x);
            Ks[wl*192 + 96 + j] = f2bf(kk.y);
        }
    }
    __syncthreads();

    int wl   = tid >> 6;        // wave id 0..3 = column
    int lane = tid & 63;
    int li   = lane & 15;
    int g    = lane >> 4;
    int w    = w0 + wl;
    unsigned short* accCn = accC + (long)n*PX*16;

    #pragma unroll
    for (int ht = 0; ht < 6; ht++) {
        int hglob = ht*16 + li;
        float2 qq = Qpn[hglob*W + w];
        float qx = qq.x * LOG2E, qy = qq.y * LOG2E;
        float m  = fabsf(qx)*g0 + fabsf(qy)*g1;

        v4f acc = {};
        float sp = 0.f;
        #pragma unroll
        for (int kc = 0; kc < 3; kc++) {
            int j0 = kc*32 + g*8;
            v8s bv = *(const v8s*)&Vt[wl*VT_WS + li*104 + j0];
            v8s kxv = *(const v8s*)&Ks[wl*192 + j0];
            v8s kyv = *(const v8s*)&Ks[wl*192 + 96 + j0];
            v8s af;
            #pragma unroll
            for (int e = 0; e < 8; e++) {
                float e2 = bf2f((unsigned short)kxv[e])*qx
                         + bf2f((unsigned short)kyv[e])*qy - m;
                float p = __builtin_amdgcn_exp2f(e2);
                p = (j0 + e == hglob) ? 0.0f : p;
                sp += p;
                af[e] = (short)f2bf(p);
            }
            acc = __builtin_amdgcn_mfma_f32_16x16x32_bf16(af, bv, acc, 0, 0, 0);
        }
        sp += __shfl_xor(sp, 16);
        sp += __shfl_xor(sp, 32);
        if (lane < 16)
            sC[((long)n*H + hglob)*W + w] = sp;

        #pragma unroll
        for (int rr = 0; rr < 4; rr++) {
            int h2 = ht*16 + g*4 + rr;
            accCn[((long)h2*W + w)*16 + li] = f2bf(acc[rr]);
        }
    }
}

// Row (W) attention as MFMA, LDS-free. K in planar bf16 (8 VGPR/chunk vs 16),
// __launch_bounds__(256,3) caps VGPR at ~168 to restore occupancy.
__global__ __launch_bounds__(256, 3)
void row_attn_kernel(const float2* __restrict__ Qp,
                     const unsigned short* __restrict__ Kb,
                     const unsigned short* __restrict__ Vbp,
                     const float* __restrict__ gmp,
                     const unsigned short* __restrict__ accC, const float* __restrict__ sC,
                     const float* __restrict__ xres, long xn_s, long xc_s,
                     float* __restrict__ out, long on_s, long oc_s,
                     const float* __restrict__ gamma_p)
{
    const int chunk = (NIMG*(H/2)) / 8;   // 144
    int bid = blockIdx.x;
    int swz = (bid & 7)*chunk + (bid >> 3);
    int n   = swz / (H/2);
    int h0  = (swz - n*(H/2)) * 2;
    int tid = threadIdx.x;

    const float2* Qpn = Qp + n*PX;
    const unsigned short* Vrn = Vbp + (long)n*PX*16;   // [h][c][w]
    float g0, g1;
    gm_reduce(gmp, n, g0, g1);

    int wv   = tid >> 6;        // 0..3
    int r    = wv >> 1;
    int half = wv & 1;
    int lane = tid & 63;
    int li   = lane & 15;
    int g    = lane >> 4;
    int h    = h0 + r;

    float qx[6], qy[6], mW[6];
    #pragma unroll
    for (int t = 0; t < 6; t++) {
        int w = (half*6 + t)*16 + li;
        float2 qq = Qpn[h*W + w];
        float lqx = qq.x * LOG2E, lqy = qq.y * LOG2E;
        qx[t] = lqx; qy[t] = lqy;
        mW[t] = fabsf(lqx)*g0 + fabsf(lqy)*g1;
    }

    v4f acc[6] = {};
    float sp[6] = {0.f,0.f,0.f,0.f,0.f,0.f};

    const unsigned short* Vrow = Vrn + (long)h*16*W + (long)li*W;
    const unsigned short* Kxr  = Kb + ((long)(n*2+0)*H + h)*W;
    const unsigned short* Kyr  = Kb + ((long)(n*2+1)*H + h)*W;

    #pragma unroll
    for (int kc = 0; kc < 6; kc++) {
        int j0 = kc*32 + g*8;
        v8s af = *(const v8s*)(Vrow + j0);                 // 16B contiguous
        v8s kx = *(const v8s*)(Kxr + j0);
        v8s ky = *(const v8s*)(Kyr + j0);
        #pragma unroll
        for (int t = 0; t < 6; t++) {
            v8s bf;
            float sl = sp[t];
            #pragma unroll
            for (int e = 0; e < 8; e++) {
                float ev = bf2f((unsigned short)kx[e])*qx[t]
                         + bf2f((unsigned short)ky[e])*qy[t];
                float p = __builtin_amdgcn_exp2f(ev - mW[t]);
                sl += p;
                bf[e] = (short)f2bf(p);
            }
            sp[t] = sl;
            acc[t] = __builtin_amdgcn_mfma_f32_16x16x32_bf16(af, bf, acc[t], 0, 0, 0);
        }
    }

    float gam = gamma_p[0];
    #pragma unroll
    for (int t = 0; t < 6; t++) {
        float s = sp[t];
        s += __shfl_xor(s, 16);
        s += __shfl_xor(s, 32);
        int w = (half*6 + t)*16 + li;
        float st = sC[((long)n*H + h)*W + w] + s;
        float inv = 1.0f / st;
        long po = (long)h*W + w;
        const unsigned short* cap = accC + (((long)n*H + h)*W + w)*16 + g*4;
        #pragma unroll
        for (int rr = 0; rr < 4; rr++) {
            int c = g*4 + rr;   // D: row = (lane>>4)*4 + reg
            float ac = bf2f(cap[rr]);
            float tot = (acc[t][rr] + ac) * inv;
            out[(long)n*on_s + (long)c*oc_s + po] =
                gam*tot + xres[(long)n*xn_s + (long)c*xc_s + po];
        }
    }
}

extern "C" void kernel_launch(void* const* d_in, const int* in_sizes, int n_in,
                              void* d_out, int out_size, void* d_ws, size_t ws_size,
                              hipStream_t stream) {
    const float* cost = (const float*)d_in[0];   // (1,16,24,96,192)
    const float* q_w  = (const float*)d_in[1];
    const float* q_b  = (const float*)d_in[2];
    const float* k_w  = (const float*)d_in[3];
    const float* k_b  = (const float*)d_in[4];
    const float* v_w  = (const float*)d_in[5];
    const float* v_b  = (const float*)d_in[6];
    const float* gamma= (const float*)d_in[7];
    float* out = (float*)d_out;
    float* ws  = (float*)d_ws;

    float2*  Qp = (float2*)(ws + QP_OFF);
    float2*  Kp = (float2*)(ws + KP_OFF);
    ushort4* Vb4 = (ushort4*)(ws + VB4_OFF);
    unsigned short* Vbp = (unsigned short*)(ws + VBP_OFF);
    unsigned short* Kb  = (unsigned short*)(ws + KB_OFF);
    float*   gmp = ws + GM_OFF;
    float*   sC  = ws + SC_OFF;
    unsigned short* aC = (unsigned short*)(ws + ACC_OFF);

    const int qkv_blocks = (NIMG*PX)/256;   // 1728
    const int col_blocks = NIMG*48;         // 1152
    const int row_blocks = NIMG*(H/2);      // 1152

    // ---- pass 1: x = cost_volume [c][n][h][w] (n stride PX, c stride 24*PX) ----
    qkv_kernel<<<qkv_blocks, 256, 0, stream>>>(
        cost, (long)PX, (long)NIMG*PX,
        q_w, q_b, k_w, k_b, v_w, v_b, Qp, Kp, Vb4, Vbp, Kb);
    gmax_kernel<<<NIMG*8, 256, 0, stream>>>(Kp, gmp);
    col_attn_kernel<<<col_blocks, 256, 0, stream>>>(
        Qp, Kp, Vb4, gmp, aC, sC);
    row_attn_kernel<<<row_blocks, 256, 0, stream>>>(
        Qp, Kb, Vbp, gmp, aC, sC,
        cost, (long)PX, (long)NIMG*PX,
        out,  (long)PX, (long)NIMG*PX,
        gamma);

    // ---- pass 2: x = d_out (same strides; per-thread same-element RMW is safe) ----
    qkv_kernel<<<qkv_blocks, 256, 0, stream>>>(
        out, (long)PX, (long)NIMG*PX,
        q_w, q_b, k_w, k_b, v_w, v_b, Qp, Kp, Vb4, Vbp, Kb);
    gmax_kernel<<<NIMG*8, 256, 0, stream>>>(Kp, gmp);
    col_attn_kernel<<<col_blocks, 256, 0, stream>>>(
        Qp, Kp, Vb4, gmp, aC, sC);
    row_attn_kernel<<<row_blocks, 256, 0, stream>>>(
        Qp, Kb, Vbp, gmp, aC, sC,
        out, (long)PX, (long)NIMG*PX,
        out, (long)PX, (long)NIMG*PX,
        gamma);
}

// Round 23
// 155.302 us; speedup vs baseline: 2.8022x; 2.8022x over previous
//
#include <hip/hip_runtime.h>

#define C 16
#define NIMG 24
#define H 96
#define W 192
#define PX (H*W)            // 18432
#define LOG2E 1.44269504088896f

typedef float v2f  __attribute__((ext_vector_type(2)));
typedef float v4f  __attribute__((ext_vector_type(4)));
typedef short v8s  __attribute__((ext_vector_type(8)));

// workspace float offsets
#define QP_OFF 0                                // float2 [n][px]
#define KP_OFF (NIMG*PX*2)                      // float2 [n][px]
#define VB4_OFF (2*NIMG*PX*2)                   // ushort4 [n][h][c4][w] (bf16 x4ch)
#define VBP_OFF (VB4_OFF + NIMG*PX*8)           // ushort [n][h][c][w] (bf16 planar)
#define KB_OFF  (VBP_OFF + NIMG*PX*8)           // ushort [n][2][h][w] (bf16 planar K)
#define CMAX_OFF (KB_OFF + NIMG*PX)             // float [n][2][W]
#define RMAX_OFF (CMAX_OFF + NIMG*2*W)          // float [n][2][H]
#define SC_OFF   (RMAX_OFF + NIMG*2*H)          // float s_col [n][h][w]
#define ACC_OFF  (SC_OFF + NIMG*PX)             // ushort accC [n][h][w][c]

__device__ __forceinline__ unsigned short f2bf(float x) {
    union { float f; unsigned u; } v; v.f = x;
    unsigned r = v.u + 0x7fffu + ((v.u >> 16) & 1u);   // RNE
    return (unsigned short)(r >> 16);
}
__device__ __forceinline__ float bf2f(unsigned short u) {
    union { unsigned u; float f; } v; v.u = ((unsigned)u) << 16;
    return v.f;
}

__global__ __launch_bounds__(256)
void qkv_kernel(const float* __restrict__ x, long xn_s, long xc_s,
                const float* __restrict__ qw, const float* __restrict__ qb,
                const float* __restrict__ kw, const float* __restrict__ kb,
                const float* __restrict__ vw, const float* __restrict__ vb,
                float2* __restrict__ Qp, float2* __restrict__ Kp,
                ushort4* __restrict__ Vb4, unsigned short* __restrict__ Vbp,
                unsigned short* __restrict__ Kb,
                float* __restrict__ cmax_zero)
{
    __shared__ float wq[2*C+2], wk[2*C+2], wv[C*C+C];
    int tid = threadIdx.x;
    if (tid < 2*C) { wq[tid] = qw[tid]; wk[tid] = kw[tid]; }
    if (tid < 2)   { wq[2*C+tid] = qb[tid]; wk[2*C+tid] = kb[tid]; }
    if (tid < C*C) wv[tid] = vw[tid];
    if (tid < C)   wv[C*C+tid] = vb[tid];

    // fold cmax zero-init into the first 36 blocks (consumed by stats kernel)
    if (blockIdx.x < 36) {
        int zi = blockIdx.x*256 + tid;
        if (zi < NIMG*2*W) cmax_zero[zi] = 0.0f;
    }
    __syncthreads();

    int id = blockIdx.x*256 + tid;        // 0 .. 442367
    int n  = id / PX;
    int p  = id - n*PX;
    int h  = p / W;
    int w  = p - h*W;
    const float* xp = x + (long)n*xn_s + p;

    float xv[C];
    #pragma unroll
    for (int c = 0; c < C; c++) xv[c] = xp[(long)c*xc_s];

    float q0 = wq[2*C], q1 = wq[2*C+1];
    float k0 = wk[2*C], k1 = wk[2*C+1];
    #pragma unroll
    for (int c = 0; c < C; c++) {
        q0 += wq[c]*xv[c];   q1 += wq[C+c]*xv[c];
        k0 += wk[c]*xv[c];   k1 += wk[C+c]*xv[c];
    }
    Qp[id] = make_float2(q0, q1);
    Kp[id] = make_float2(k0, k1);
    Kb[((long)(n*2+0)*H + h)*W + w] = f2bf(k0);
    Kb[((long)(n*2+1)*H + h)*W + w] = f2bf(k1);

    float vv[C];
    #pragma unroll
    for (int o = 0; o < C; o++) {
        float a = wv[C*C+o];
        #pragma unroll
        for (int c = 0; c < C; c++) a += wv[o*C+c]*xv[c];
        vv[o] = a;
    }
    unsigned short vb16[C];
    #pragma unroll
    for (int o = 0; o < C; o++) vb16[o] = f2bf(vv[o]);

    // interleaved [n][h][c4][w] (ushort4) for col staging
    #pragma unroll
    for (int c4 = 0; c4 < 4; c4++) {
        ushort4 u;
        u.x = vb16[c4*4+0]; u.y = vb16[c4*4+1];
        u.z = vb16[c4*4+2]; u.w = vb16[c4*4+3];
        Vb4[(((long)n*H + h)*4 + c4)*W + w] = u;
    }
    // planar [n][h][c][w] for row fragment loads
    #pragma unroll
    for (int o = 0; o < C; o++)
        Vbp[(((long)n*H + h)*16 + o)*W + w] = vb16[o];
}

// 96 blocks: (n, h-slice of 24 rows). cmax via uint atomicMax, rmax direct.
__global__ __launch_bounds__(192)
void stats_kernel(const float2* __restrict__ Kp,
                  float* __restrict__ cmax, float* __restrict__ rmax)
{
    int bid = blockIdx.x;
    int n   = bid >> 2;
    int h0  = (bid & 3) * 24;
    int tid = threadIdx.x;
    const float2* Kpn = Kp + n*PX;

    // column max over this 24-row slice (w = tid, coalesced)
    float c0 = 0.f, c1 = 0.f;
    #pragma unroll 4
    for (int h = 0; h < 24; h++) {
        float2 k = Kpn[(h0+h)*W + tid];
        c0 = fmaxf(c0, fabsf(k.x));
        c1 = fmaxf(c1, fabsf(k.y));
    }
    atomicMax((unsigned*)&cmax[n*2*W + tid],     __float_as_uint(c0));
    atomicMax((unsigned*)&cmax[n*2*W + W + tid], __float_as_uint(c1));

    // row max: 8 threads per row, 24 w each, shuffle-merged
    int r = tid >> 3, seg = tid & 7;
    float r0 = 0.f, r1 = 0.f;
    const float2* kr = Kpn + (h0+r)*W + seg*24;
    #pragma unroll 4
    for (int j = 0; j < 24; j++) {
        float2 k = kr[j];
        r0 = fmaxf(r0, fabsf(k.x));
        r1 = fmaxf(r1, fabsf(k.y));
    }
    r0 = fmaxf(r0, __shfl_xor(r0, 1)); r0 = fmaxf(r0, __shfl_xor(r0, 2)); r0 = fmaxf(r0, __shfl_xor(r0, 4));
    r1 = fmaxf(r1, __shfl_xor(r1, 1)); r1 = fmaxf(r1, __shfl_xor(r1, 2)); r1 = fmaxf(r1, __shfl_xor(r1, 4));
    if (seg == 0) {
        rmax[n*2*H + h0 + r]     = r0;
        rmax[n*2*H + H + h0 + r] = r1;
    }
}

// Column (H) attention as MFMA (R18 structure, bf16 V staging reads).
#define VT_WS 1672   // per-w Vt stride in ushorts: 16*104 + 8 pad
__global__ __launch_bounds__(256)
void col_attn_kernel(const float2* __restrict__ Qp, const float2* __restrict__ Kp,
                     const ushort4* __restrict__ Vb4,
                     const float* __restrict__ cmax, const float* __restrict__ rmax,
                     unsigned short* __restrict__ accC, float* __restrict__ sC)
{
    __shared__ unsigned short Vt[4*VT_WS];      // V^T: [wl][c][j] bf16, j-pad 104
    __shared__ unsigned short Ks[4*2*96];       // K:   [wl][ch][j] bf16
    __shared__ float2         Qs[4*96];         // q (log2-scaled): [wl][h]
    __shared__ float          Ms[4*96];         // shift bound m:   [wl][h]

    const int chunk = (NIMG*48) / 8;            // 144 ; 1152 % 8 == 0
    int bid = blockIdx.x;
    int swz = (bid & 7)*chunk + (bid >> 3);
    int n   = swz / 48;
    int wg  = swz - n*48;
    int w0  = wg*4;
    int tid = threadIdx.x;

    const float2* Qpn = Qp + n*PX;
    const float2* Kpn = Kp + n*PX;
    const ushort4* Vbn = Vb4 + (long)n*PX*4;

    // ---- stage V^T (1536 ushort4, 6/thread) ----
    #pragma unroll
    for (int i = 0; i < 6; i++) {
        int idx = i*256 + tid;        // 0..1535
        int wl  = idx & 3;
        int c4  = (idx >> 2) & 3;
        int j   = idx >> 4;           // 0..95
        ushort4 v = Vbn[((long)j*4 + c4)*W + w0 + wl];
        int b = wl*VT_WS + (c4*4)*104 + j;
        Vt[b        ] = v.x;
        Vt[b + 104  ] = v.y;
        Vt[b + 208  ] = v.z;
        Vt[b + 312  ] = v.w;
    }
    // ---- stage K (384 float2 -> bf16) ----
    #pragma unroll
    for (int i = 0; i < 2; i++) {
        int idx = i*256 + tid;
        if (idx < 384) {
            int wl = idx & 3;
            int j  = idx >> 2;
            float2 kk = Kpn[j*W + w0 + wl];
            Ks[wl*192 + j]      = f2bf(kk.x);
            Ks[wl*192 + 96 + j] = f2bf(kk.y);
        }
    }
    // ---- stage Q (log2 domain) + m bound ----
    #pragma unroll
    for (int i = 0; i < 2; i++) {
        int idx = i*256 + tid;
        if (idx < 384) {
            int wl = idx & 3;
            int h  = idx >> 2;
            int w  = w0 + wl;
            float2 qq = Qpn[h*W + w];
            float qx = qq.x * LOG2E, qy = qq.y * LOG2E;
            float c0 = cmax[n*2*W + w], c1 = cmax[n*2*W + W + w];
            float r0 = rmax[n*2*H + h], r1 = rmax[n*2*H + H + h];
            float ax = fabsf(qx), ay = fabsf(qy);
            Qs[wl*96 + h] = make_float2(qx, qy);
            Ms[wl*96 + h] = fmaxf(ax*c0 + ay*c1, ax*r0 + ay*r1);
        }
    }
    __syncthreads();

    int wl   = tid >> 6;        // wave id 0..3 = column
    int lane = tid & 63;
    int li   = lane & 15;
    int g    = lane >> 4;
    int w    = w0 + wl;
    unsigned short* accCn = accC + (long)n*PX*16;

    #pragma unroll
    for (int ht = 0; ht < 6; ht++) {
        int hglob = ht*16 + li;
        float2 q = Qs[wl*96 + hglob];
        float  m = Ms[wl*96 + hglob];

        v4f acc = {};
        float sp = 0.f;
        #pragma unroll
        for (int kc = 0; kc < 3; kc++) {
            int j0 = kc*32 + g*8;
            v8s bv = *(const v8s*)&Vt[wl*VT_WS + li*104 + j0];
            v8s kxv = *(const v8s*)&Ks[wl*192 + j0];
            v8s kyv = *(const v8s*)&Ks[wl*192 + 96 + j0];
            v8s af;
            #pragma unroll
            for (int e = 0; e < 8; e++) {
                float e2 = bf2f((unsigned short)kxv[e])*q.x
                         + bf2f((unsigned short)kyv[e])*q.y - m;
                float p = __builtin_amdgcn_exp2f(e2);
                p = (j0 + e == hglob) ? 0.0f : p;
                sp += p;
                af[e] = (short)f2bf(p);
            }
            acc = __builtin_amdgcn_mfma_f32_16x16x32_bf16(af, bv, acc, 0, 0, 0);
        }
        sp += __shfl_xor(sp, 16);
        sp += __shfl_xor(sp, 32);
        if (lane < 16)
            sC[((long)n*H + hglob)*W + w] = sp;

        #pragma unroll
        for (int rr = 0; rr < 4; rr++) {
            int h2 = ht*16 + g*4 + rr;
            accCn[((long)h2*W + w)*16 + li] = f2bf(acc[rr]);
        }
    }
}

// Row (W) attention as MFMA, LDS-free. K planar bf16 (fewer regs than fp32),
// NO launch_bounds clamp (R11/R12/R22 lesson: clamps spill).
__global__ __launch_bounds__(256)
void row_attn_kernel(const float2* __restrict__ Qp,
                     const unsigned short* __restrict__ Kb,
                     const unsigned short* __restrict__ Vbp,
                     const float* __restrict__ cmax, const float* __restrict__ rmax,
                     const unsigned short* __restrict__ accC, const float* __restrict__ sC,
                     const float* __restrict__ xres, long xn_s, long xc_s,
                     float* __restrict__ out, long on_s, long oc_s,
                     const float* __restrict__ gamma_p)
{
    const int chunk = (NIMG*(H/2)) / 8;   // 144
    int bid = blockIdx.x;
    int swz = (bid & 7)*chunk + (bid >> 3);
    int n   = swz / (H/2);
    int h0  = (swz - n*(H/2)) * 2;
    int tid = threadIdx.x;

    const float2* Qpn = Qp + n*PX;
    const unsigned short* Vrn = Vbp + (long)n*PX*16;   // [h][c][w]

    int wv   = tid >> 6;        // 0..3
    int r    = wv >> 1;
    int half = wv & 1;
    int lane = tid & 63;
    int li   = lane & 15;
    int g    = lane >> 4;
    int h    = h0 + r;

    float r0 = rmax[n*2*H + h], r1 = rmax[n*2*H + H + h];
    float qx[6], qy[6], mW[6];
    #pragma unroll
    for (int t = 0; t < 6; t++) {
        int w = (half*6 + t)*16 + li;
        float2 qq = Qpn[h*W + w];
        float c0 = cmax[n*2*W + w], c1 = cmax[n*2*W + W + w];
        float lqx = qq.x * LOG2E, lqy = qq.y * LOG2E;
        qx[t] = lqx; qy[t] = lqy;
        mW[t] = fmaxf(fabsf(lqx)*c0 + fabsf(lqy)*c1, fabsf(lqx)*r0 + fabsf(lqy)*r1);
    }

    v4f acc[6] = {};
    float sp[6] = {0.f,0.f,0.f,0.f,0.f,0.f};

    const unsigned short* Vrow = Vrn + (long)h*16*W + (long)li*W;
    const unsigned short* Kxr  = Kb + ((long)(n*2+0)*H + h)*W;
    const unsigned short* Kyr  = Kb + ((long)(n*2+1)*H + h)*W;

    #pragma unroll
    for (int kc = 0; kc < 6; kc++) {
        int j0 = kc*32 + g*8;
        v8s af = *(const v8s*)(Vrow + j0);                 // 16B contiguous
        v8s kx = *(const v8s*)(Kxr + j0);
        v8s ky = *(const v8s*)(Kyr + j0);
        #pragma unroll
        for (int t = 0; t < 6; t++) {
            v8s bf;
            float sl = sp[t];
            #pragma unroll
            for (int e = 0; e < 8; e++) {
                float ev = bf2f((unsigned short)kx[e])*qx[t]
                         + bf2f((unsigned short)ky[e])*qy[t];
                float p = __builtin_amdgcn_exp2f(ev - mW[t]);
                sl += p;
                bf[e] = (short)f2bf(p);
            }
            sp[t] = sl;
            acc[t] = __builtin_amdgcn_mfma_f32_16x16x32_bf16(af, bf, acc[t], 0, 0, 0);
        }
    }

    float gam = gamma_p[0];
    #pragma unroll
    for (int t = 0; t < 6; t++) {
        float s = sp[t];
        s += __shfl_xor(s, 16);
        s += __shfl_xor(s, 32);
        int w = (half*6 + t)*16 + li;
        float st = sC[((long)n*H + h)*W + w] + s;
        float inv = 1.0f / st;
        long po = (long)h*W + w;
        const unsigned short* cap = accC + (((long)n*H + h)*W + w)*16 + g*4;
        #pragma unroll
        for (int rr = 0; rr < 4; rr++) {
            int c = g*4 + rr;   // D: row = (lane>>4)*4 + reg
            float ac = bf2f(cap[rr]);
            float tot = (acc[t][rr] + ac) * inv;
            out[(long)n*on_s + (long)c*oc_s + po] =
                gam*tot + xres[(long)n*xn_s + (long)c*xc_s + po];
        }
    }
}

extern "C" void kernel_launch(void* const* d_in, const int* in_sizes, int n_in,
                              void* d_out, int out_size, void* d_ws, size_t ws_size,
                              hipStream_t stream) {
    const float* cost = (const float*)d_in[0];   // (1,16,24,96,192)
    const float* q_w  = (const float*)d_in[1];
    const float* q_b  = (const float*)d_in[2];
    const float* k_w  = (const float*)d_in[3];
    const float* k_b  = (const float*)d_in[4];
    const float* v_w  = (const float*)d_in[5];
    const float* v_b  = (const float*)d_in[6];
    const float* gamma= (const float*)d_in[7];
    float* out = (float*)d_out;
    float* ws  = (float*)d_ws;

    float2*  Qp = (float2*)(ws + QP_OFF);
    float2*  Kp = (float2*)(ws + KP_OFF);
    ushort4* Vb4 = (ushort4*)(ws + VB4_OFF);
    unsigned short* Vbp = (unsigned short*)(ws + VBP_OFF);
    unsigned short* Kb  = (unsigned short*)(ws + KB_OFF);
    float*   cm = ws + CMAX_OFF;
    float*   rm = ws + RMAX_OFF;
    float*   sC = ws + SC_OFF;
    unsigned short* aC = (unsigned short*)(ws + ACC_OFF);

    const int qkv_blocks  = (NIMG*PX)/256;   // 1728
    const int stat_blocks = NIMG*4;          // 96
    const int col_blocks  = NIMG*48;         // 1152
    const int row_blocks  = NIMG*(H/2);      // 1152

    // ---- pass 1: x = cost_volume [c][n][h][w] (n stride PX, c stride 24*PX) ----
    qkv_kernel<<<qkv_blocks, 256, 0, stream>>>(
        cost, (long)PX, (long)NIMG*PX,
        q_w, q_b, k_w, k_b, v_w, v_b, Qp, Kp, Vb4, Vbp, Kb, cm);
    stats_kernel<<<stat_blocks, 192, 0, stream>>>(Kp, cm, rm);
    col_attn_kernel<<<col_blocks, 256, 0, stream>>>(
        Qp, Kp, Vb4, cm, rm, aC, sC);
    row_attn_kernel<<<row_blocks, 256, 0, stream>>>(
        Qp, Kb, Vbp, cm, rm, aC, sC,
        cost, (long)PX, (long)NIMG*PX,
        out,  (long)PX, (long)NIMG*PX,
        gamma);

    // ---- pass 2: x = d_out (same strides; per-thread same-element RMW is safe) ----
    qkv_kernel<<<qkv_blocks, 256, 0, stream>>>(
        out, (long)PX, (long)NIMG*PX,
        q_w, q_b, k_w, k_b, v_w, v_b, Qp, Kp, Vb4, Vbp, Kb, cm);
    stats_kernel<<<stat_blocks, 192, 0, stream>>>(Kp, cm, rm);
    col_attn_kernel<<<col_blocks, 256, 0, stream>>>(
        Qp, Kp, Vb4, cm, rm, aC, sC);
    row_attn_kernel<<<row_blocks, 256, 0, stream>>>(
        Qp, Kb, Vbp, cm, rm, aC, sC,
        out, (long)PX, (long)NIMG*PX,
        out, (long)PX, (long)NIMG*PX,
        gamma);
}